// Round 1
// baseline (220.683 us; speedup 1.0000x reference)
//
#include <hip/hip_runtime.h>

// Problem constants
#define B_N 4096
#define TB 17            // batches per main block (241 blocks * 17 = 4097 >= 4096)
#define NMAIN 241
#define SQUARINGS 8

// ---- workspace layout (float offsets) ----
#define OFF_W5   0        // 5 x [64][256]: ZQ, LK, LV, CK, CV
#define OFF_B5   81920    // 5 x [256] folded biases
#define OFF_AK   83200    // [16][256] action_chart_emb @ Wk
#define OFF_AV   87296    // [16][256] action_chart_emb @ Wv
#define OFF_CHK  91392    // [32][256] chart_emb @ Wk
#define OFF_CHV  99584    // [32][256] chart_emb @ Wv
#define OFF_M    107776   // [256][64] Wo @ form_W
#define OFF_G    124160   // [64][64]  form_W^T @ form_W
#define OFF_RS   128256   // 1/sigma
#define OFF_A    128320   // [4096]
#define OFF_Bc   132416   // [4096]
// total 136512 floats = 546 KB

// ---- LDS layout (float offsets) ----
#define S_ZS    0         // [17][68]
#define S_AZS   1156
#define S_ACZS  2312
#define S_RWS   3468      // [17][36]
#define S_ARWS  4080      // [17][20]   (S_ZS..4420 reused as M-chunk stage [64][68])
#define S_STAGE 0
#define S_CS    4420      // [17][68]
#define S_ES    5576      // [17][68]
#define S_QFP   6732      // [17][260]  q, later feat_pre
#define S_SW    11152     // [17][52]   scores/weights: [0..15]=achart [16..47]=chart [48]=lat [49]=code
#define S_G     12036     // [17][68]
#define S_RED   13192     // [17][16] reduction partials
#define SMEM_N  13480     // 53.9 KB

// ===================== K1: fold weights =====================
__global__ __launch_bounds__(256)
void k1_fold(const float* __restrict__ chart_emb, const float* __restrict__ a_chart_emb,
             const float* __restrict__ zW, const float* __restrict__ zb,
             const float* __restrict__ latW, const float* __restrict__ latb,
             const float* __restrict__ codeW, const float* __restrict__ codeb,
             const float* __restrict__ Wq, const float* __restrict__ Wk,
             const float* __restrict__ Wv, const float* __restrict__ Wo,
             const float* __restrict__ fW, float* __restrict__ ws) {
  int e = blockIdx.x * 256 + threadIdx.x;   // grid sized exactly: e < 128256
  if (e < 81920) {                           // ZQ, LK, LV, CK, CV
    int u = e >> 14;
    int r = e & 16383;
    int i = r >> 8, j = r & 255;
    const float* A  = (u == 0) ? zW : (u <= 2 ? latW : codeW);
    const float* Bm = (u == 0) ? Wq : ((u == 1 || u == 3) ? Wk : Wv);
    const float* arow = A + i * 256;
    float acc = 0.f;
    #pragma unroll 8
    for (int k = 0; k < 256; ++k) acc += arow[k] * Bm[k * 256 + j];
    ws[e] = acc;
  } else if (e < 83200) {                    // folded biases
    int r = e - 81920;
    int u = r >> 8, j = r & 255;
    const float* A  = (u == 0) ? zb : (u <= 2 ? latb : codeb);
    const float* Bm = (u == 0) ? Wq : ((u == 1 || u == 3) ? Wk : Wv);
    float acc = 0.f;
    #pragma unroll 8
    for (int k = 0; k < 256; ++k) acc += A[k] * Bm[k * 256 + j];
    ws[e] = acc;
  } else if (e < 91392) {                    // AK, AV
    int r = e - 83200;
    const float* Bm = (r < 4096) ? Wk : Wv;
    int rr = r & 4095;
    int a = rr >> 8, j = rr & 255;
    const float* arow = a_chart_emb + a * 256;
    float acc = 0.f;
    #pragma unroll 8
    for (int k = 0; k < 256; ++k) acc += arow[k] * Bm[k * 256 + j];
    ws[e] = acc;
  } else if (e < 107776) {                   // CHK, CHV
    int r = e - 91392;
    const float* Bm = (r < 8192) ? Wk : Wv;
    int rr = r & 8191;
    int c = rr >> 8, j = rr & 255;
    const float* arow = chart_emb + c * 256;
    float acc = 0.f;
    #pragma unroll 8
    for (int k = 0; k < 256; ++k) acc += arow[k] * Bm[k * 256 + j];
    ws[e] = acc;
  } else if (e < 124160) {                   // M = Wo @ form_W
    int r = e - 107776;
    int i = r >> 6, j = r & 63;
    float acc = 0.f;
    #pragma unroll 8
    for (int k = 0; k < 256; ++k) acc += Wo[i * 256 + k] * fW[k * 64 + j];
    ws[e] = acc;
  } else {                                   // G = form_W^T @ form_W
    int r = e - 124160;
    int i = r >> 6, j = r & 63;
    float acc = 0.f;
    #pragma unroll 8
    for (int k = 0; k < 256; ++k) acc += fW[k * 64 + i] * fW[k * 64 + j];
    ws[e] = acc;
  }
}

// per-thread: out[bi] = bias[t] + sum_i in[bi][i] * W5[u][i][t]
__device__ __forceinline__ void matvec17(const float* __restrict__ ws, int u,
                                         const float* __restrict__ sin_,
                                         int t, float* out) {
  float acc[TB];
  float bias = ws[OFF_B5 + u * 256 + t];
  #pragma unroll
  for (int bi = 0; bi < TB; ++bi) acc[bi] = bias;
  const float* wc = ws + OFF_W5 + u * 16384 + t;
  #pragma unroll 2
  for (int k4 = 0; k4 < 16; ++k4) {
    float w0 = wc[(k4 * 4 + 0) * 256];
    float w1 = wc[(k4 * 4 + 1) * 256];
    float w2 = wc[(k4 * 4 + 2) * 256];
    float w3 = wc[(k4 * 4 + 3) * 256];
    #pragma unroll
    for (int bi = 0; bi < TB; ++bi) {
      float4 x4 = *reinterpret_cast<const float4*>(&sin_[bi * 68 + k4 * 4]);
      acc[bi] += x4.x * w0 + x4.y * w1 + x4.z * w2 + x4.w * w3;
    }
  }
  #pragma unroll
  for (int bi = 0; bi < TB; ++bi) out[bi] = acc[bi];
}

// ===================== K2: main =====================
__global__ __launch_bounds__(256)
void k2_main(const float* __restrict__ z, const float* __restrict__ rw,
             const float* __restrict__ az, const float* __restrict__ arw,
             const float* __restrict__ acz, const float* __restrict__ ctrl,
             const float* __restrict__ ecov, const float* __restrict__ ch_anchor,
             const float* __restrict__ ach_anchor, const float* __restrict__ fb,
             float* __restrict__ ws) {
  __shared__ float sm[SMEM_N];
  const int t  = threadIdx.x;
  const int wv = t >> 6;
  const int ln = t & 63;

  if (blockIdx.x == 0) {
    // ---------- sigma block: power-by-squaring on G (64x64) ----------
    float* GO = sm;            // [64][68] original G
    float* HA = sm + 4352;
    float* HB = sm + 8704;
    for (int e = t; e < 4096; e += 256) {
      int i = e >> 6, j = e & 63;
      GO[i * 68 + j] = ws[OFF_G + e];
    }
    __syncthreads();
    {
      float tv = (t < 64) ? GO[t * 68 + t] : 0.f;
      #pragma unroll
      for (int m = 32; m >= 1; m >>= 1) tv += __shfl_xor(tv, m, 64);
      if (t == 0) sm[13056] = (tv > 0.f) ? 1.f / tv : 0.f;
    }
    __syncthreads();
    {
      float inv0 = sm[13056];
      for (int e = t; e < 4096; e += 256) {
        int i = e >> 6, j = e & 63;
        HA[i * 68 + j] = GO[i * 68 + j] * inv0;
      }
    }
    __syncthreads();
    for (int it = 0; it < SQUARINGS; ++it) {
      float* src = (it & 1) ? HB : HA;
      float* dst = (it & 1) ? HA : HB;
      float cb[64];
      #pragma unroll
      for (int k = 0; k < 64; ++k) cb[k] = src[k * 68 + ln];
      #pragma unroll
      for (int r = 0; r < 16; ++r) {
        int i = r * 4 + wv;            // wave-uniform row -> broadcast reads
        float acc = 0.f;
        #pragma unroll
        for (int k4 = 0; k4 < 16; ++k4) {
          float4 a4 = *reinterpret_cast<const float4*>(&src[i * 68 + k4 * 4]);
          acc += a4.x * cb[k4 * 4] + a4.y * cb[k4 * 4 + 1] + a4.z * cb[k4 * 4 + 2] + a4.w * cb[k4 * 4 + 3];
        }
        dst[i * 68 + ln] = acc;
      }
      __syncthreads();
      {
        float tv = (t < 64) ? dst[t * 68 + t] : 0.f;
        #pragma unroll
        for (int m = 32; m >= 1; m >>= 1) tv += __shfl_xor(tv, m, 64);
        if (t == 0) sm[13056] = (tv > 0.f) ? 1.f / tv : 0.f;
      }
      __syncthreads();
      {
        float sc = sm[13056];
        #pragma unroll
        for (int r = 0; r < 16; ++r) dst[(r * 4 + wv) * 68 + ln] *= sc;
      }
      __syncthreads();
    }
    float* H = (SQUARINGS & 1) ? HB : HA;
    if (t < 64) {                       // pick max-norm column (overlap with top eigvec)
      float cn = 0.f;
      for (int i = 0; i < 64; ++i) { float h = H[i * 68 + t]; cn += h * h; }
      float bv = cn; int bj = t;
      #pragma unroll
      for (int m = 32; m >= 1; m >>= 1) {
        float ov = __shfl_xor(bv, m, 64);
        int   oj = __shfl_xor(bj, m, 64);
        if (ov > bv || (ov == bv && oj < bj)) { bv = ov; bj = oj; }
      }
      if (t == 0) sm[13057] = (float)bj;
    }
    __syncthreads();
    {
      int jmax = (int)sm[13057];
      if (t < 64) sm[13060 + t] = H[t * 68 + jmax];
    }
    __syncthreads();
    if (t < 64) {                       // Rayleigh quotient with original fp32 G
      float vi = sm[13060 + t];
      float y = 0.f;
      #pragma unroll 4
      for (int k = 0; k < 64; ++k) y += GO[t * 68 + k] * sm[13060 + k];
      float num = vi * y, den = vi * vi;
      #pragma unroll
      for (int m = 32; m >= 1; m >>= 1) {
        num += __shfl_xor(num, m, 64);
        den += __shfl_xor(den, m, 64);
      }
      if (t == 0) {
        float lam = (den > 1e-37f) ? num / den : 0.f;
        lam = fmaxf(lam, 0.f);
        float sg = sqrtf(lam);
        ws[OFF_RS] = 1.f / fmaxf(sg, 1e-8f);
      }
    }
    return;
  }

  // ---------- main batch blocks ----------
  const int b0 = (blockIdx.x - 1) * TB;
  for (int e = t; e < TB * 64; e += 256) {
    int bi = e >> 6, d = e & 63;
    int b = b0 + bi;
    bool v = (b < B_N);
    sm[S_ZS   + bi * 68 + d] = v ? z[b * 64 + d]    : 0.f;
    sm[S_AZS  + bi * 68 + d] = v ? az[b * 64 + d]   : 0.f;
    sm[S_ACZS + bi * 68 + d] = v ? acz[b * 64 + d]  : 0.f;
    sm[S_CS   + bi * 68 + d] = v ? ctrl[b * 64 + d] : 0.f;
    sm[S_ES   + bi * 68 + d] = v ? ecov[b * 64 + d] : 0.f;
  }
  for (int e = t; e < TB * 32; e += 256) {
    int bi = e >> 5, d = e & 31; int b = b0 + bi;
    sm[S_RWS + bi * 36 + d] = (b < B_N) ? rw[b * 32 + d] : 0.f;
  }
  for (int e = t; e < TB * 16; e += 256) {
    int bi = e >> 4, d = e & 15; int b = b0 + bi;
    sm[S_ARWS + bi * 20 + d] = (b < B_N) ? arw[b * 16 + d] : 0.f;
  }
  __syncthreads();

  float vlr[TB], vcr[TB];
  {
    float qr[TB], klr[TB], kcr[TB];
    matvec17(ws, 0, sm + S_ZS,   t, qr);   // q
    #pragma unroll
    for (int bi = 0; bi < TB; ++bi) sm[S_QFP + bi * 260 + t] = qr[bi];
    matvec17(ws, 1, sm + S_AZS,  t, klr);  // k_lat
    matvec17(ws, 3, sm + S_ACZS, t, kcr);  // k_code
    // block-wide dots: q.k_lat, q.k_code, |z-az|^2, |z-acz|^2
    #pragma unroll
    for (int bi = 0; bi < TB; ++bi) {
      float pL = qr[bi] * klr[bi];
      float pC = qr[bi] * kcr[bi];
      float dL = 0.f, dC = 0.f;
      if (wv == 0) {
        float a = sm[S_ZS + bi * 68 + ln] - sm[S_AZS  + bi * 68 + ln]; dL = a * a;
        float c = sm[S_ZS + bi * 68 + ln] - sm[S_ACZS + bi * 68 + ln]; dC = c * c;
      }
      #pragma unroll
      for (int m = 32; m >= 1; m >>= 1) {
        pL += __shfl_xor(pL, m, 64);
        pC += __shfl_xor(pC, m, 64);
        dL += __shfl_xor(dL, m, 64);
        dC += __shfl_xor(dC, m, 64);
      }
      if (ln == 0) {
        sm[S_RED + bi * 16 + 0  + wv] = pL;
        sm[S_RED + bi * 16 + 4  + wv] = pC;
        sm[S_RED + bi * 16 + 8  + wv] = dL;
        sm[S_RED + bi * 16 + 12 + wv] = dC;
      }
    }
  }
  __syncthreads();
  if (t < TB) {
    float pL = 0.f, pC = 0.f, dL = 0.f, dC = 0.f;
    #pragma unroll
    for (int w = 0; w < 4; ++w) {
      pL += sm[S_RED + t * 16 + 0  + w];
      pC += sm[S_RED + t * 16 + 4  + w];
      dL += sm[S_RED + t * 16 + 8  + w];
      dC += sm[S_RED + t * 16 + 12 + w];
    }
    sm[S_SW + t * 52 + 48] = pL * 0.0625f - dL;   // lat
    sm[S_SW + t * 52 + 49] = pC * 0.0625f - dC;   // code
  }
  matvec17(ws, 2, sm + S_AZS,  t, vlr);   // v_lat
  matvec17(ws, 4, sm + S_ACZS, t, vcr);   // v_code

  // chart scores: s<16 achart, 16..47 chart
  for (int jb = t; jb < 48 * TB; jb += 256) {
    int s = jb / TB;
    int bi = jb - s * TB;
    const float* krow = (s < 16) ? (ws + OFF_AK + s * 256) : (ws + OFF_CHK + (s - 16) * 256);
    float dot = 0.f;
    #pragma unroll 4
    for (int k4 = 0; k4 < 64; ++k4) {
      float4 q4 = *reinterpret_cast<const float4*>(&sm[S_QFP + bi * 260 + k4 * 4]);
      float4 kk = *reinterpret_cast<const float4*>(&krow[k4 * 4]);
      dot += q4.x * kk.x + q4.y * kk.y + q4.z * kk.z + q4.w * kk.w;
    }
    const float* anch = (s < 16) ? (ach_anchor + s * 64) : (ch_anchor + (s - 16) * 64);
    float d2 = 0.f;
    #pragma unroll 4
    for (int d = 0; d < 64; ++d) {
      float df = sm[S_ZS + bi * 68 + d] - anch[d];
      d2 += df * df;
    }
    float rwv = (s < 16) ? sm[S_ARWS + bi * 20 + s] : sm[S_RWS + bi * 36 + (s - 16)];
    sm[S_SW + bi * 52 + s] = rwv * dot * 0.0625f - d2;
  }
  __syncthreads();

  // softmax + fold routing weights into token weights
  if (t < TB) {
    float* swr = &sm[S_SW + t * 52];
    float mx = -1e30f;
    for (int s = 0; s < 50; ++s) mx = fmaxf(mx, swr[s]);
    float sum = 0.f;
    for (int s = 0; s < 50; ++s) { float ev = __expf(swr[s] - mx); swr[s] = ev; sum += ev; }
    float inv = 1.f / sum;
    for (int j = 0; j < 16; ++j) swr[j]      *= inv * sm[S_ARWS + t * 20 + j];
    for (int k = 0; k < 32; ++k) swr[16 + k] *= inv * sm[S_RWS  + t * 36 + k];
    swr[48] *= inv;
    swr[49] *= inv;
  }
  __syncthreads();

  // feat_pre (column t), write into S_QFP
  {
    float av[16], chv[32];
    #pragma unroll
    for (int j = 0; j < 16; ++j) av[j]  = ws[OFF_AV  + j * 256 + t];
    #pragma unroll
    for (int k = 0; k < 32; ++k) chv[k] = ws[OFF_CHV + k * 256 + t];
    float fp[TB];
    #pragma unroll
    for (int bi = 0; bi < TB; ++bi) {
      const float* swr = &sm[S_SW + bi * 52];
      float acc = swr[48] * vlr[bi] + swr[49] * vcr[bi];
      #pragma unroll
      for (int j4 = 0; j4 < 4; ++j4) {
        float4 w4 = *reinterpret_cast<const float4*>(&swr[j4 * 4]);
        acc += w4.x * av[j4 * 4] + w4.y * av[j4 * 4 + 1] + w4.z * av[j4 * 4 + 2] + w4.w * av[j4 * 4 + 3];
      }
      #pragma unroll
      for (int k4 = 0; k4 < 8; ++k4) {
        float4 w4 = *reinterpret_cast<const float4*>(&swr[16 + k4 * 4]);
        acc += w4.x * chv[k4 * 4] + w4.y * chv[k4 * 4 + 1] + w4.z * chv[k4 * 4 + 2] + w4.w * chv[k4 * 4 + 3];
      }
      fp[bi] = acc;
    }
    #pragma unroll
    for (int bi = 0; bi < TB; ++bi) sm[S_QFP + bi * 260 + t] = fp[bi];
  }
  __syncthreads();

  // g = feat_pre @ M, with M staged in LDS chunks of 64 rows
  float gacc[5];
  #pragma unroll
  for (int p = 0; p < 5; ++p) gacc[p] = 0.f;
  for (int tc = 0; tc < 4; ++tc) {
    __syncthreads();
    for (int e = t; e < 4096; e += 256) {
      int tr_ = e >> 6, d = e & 63;
      sm[S_STAGE + tr_ * 68 + d] = ws[OFF_M + (tc * 64 + tr_) * 64 + d];
    }
    __syncthreads();
    #pragma unroll
    for (int p = 0; p < 5; ++p) {
      int jb = t + p * 256;
      if (jb < TB * 64) {
        int bi = jb >> 6, d = jb & 63;
        float acc = gacc[p];
        #pragma unroll
        for (int k4 = 0; k4 < 16; ++k4) {
          float4 f4 = *reinterpret_cast<const float4*>(&sm[S_QFP + bi * 260 + tc * 64 + k4 * 4]);
          acc += f4.x * sm[S_STAGE + (k4 * 4 + 0) * 68 + d]
               + f4.y * sm[S_STAGE + (k4 * 4 + 1) * 68 + d]
               + f4.z * sm[S_STAGE + (k4 * 4 + 2) * 68 + d]
               + f4.w * sm[S_STAGE + (k4 * 4 + 3) * 68 + d];
        }
        gacc[p] = acc;
      }
    }
  }
  #pragma unroll
  for (int p = 0; p < 5; ++p) {
    int jb = t + p * 256;
    if (jb < TB * 64) { int bi = jb >> 6, d = jb & 63; sm[S_G + bi * 68 + d] = gacc[p]; }
  }
  __syncthreads();

  // final per-batch dots -> A, B
  {
    float fbv = fb[ln];
    for (int bi = wv; bi < TB; bi += 4) {
      int b = b0 + bi;
      float gv = sm[S_G  + bi * 68 + ln];
      float cv = sm[S_CS + bi * 68 + ln];
      float ev = sm[S_ES + bi * 68 + ln];
      float gc = gv * cv, ge = gv * ev, ec = ev * cv, ee = ev * ev, fc = fbv * cv, fe = fbv * ev;
      #pragma unroll
      for (int m = 32; m >= 1; m >>= 1) {
        gc += __shfl_xor(gc, m, 64);
        ge += __shfl_xor(ge, m, 64);
        ec += __shfl_xor(ec, m, 64);
        ee += __shfl_xor(ee, m, 64);
        fc += __shfl_xor(fc, m, 64);
        fe += __shfl_xor(fe, m, 64);
      }
      if (ln == 0 && b < B_N) {
        float Aval, Bval;
        if (ee > 1e-8f) {
          float r = ec / ee;
          Aval = gc - ge * r;
          Bval = fc - fe * r;
        } else { Aval = gc; Bval = fc; }
        ws[OFF_A  + b] = Aval;
        ws[OFF_Bc + b] = Bval;
      }
    }
  }
}

// ===================== K3: epilogue =====================
__global__ __launch_bounds__(256)
void k3_out(const float* __restrict__ ws, float* __restrict__ out) {
  int b = blockIdx.x * 256 + threadIdx.x;
  if (b < B_N) {
    float rs = ws[OFF_RS];
    out[b] = ws[OFF_A + b] * rs + ws[OFF_Bc + b];
  }
}

extern "C" void kernel_launch(void* const* d_in, const int* in_sizes, int n_in,
                              void* d_out, int out_size, void* d_ws, size_t ws_size,
                              hipStream_t stream) {
  const float* z     = (const float*)d_in[0];
  const float* rw    = (const float*)d_in[1];
  const float* az    = (const float*)d_in[2];
  const float* arw   = (const float*)d_in[3];
  const float* acz   = (const float*)d_in[4];
  const float* ctrl  = (const float*)d_in[5];
  const float* ecov  = (const float*)d_in[6];
  const float* chemb = (const float*)d_in[7];
  const float* chanc = (const float*)d_in[8];
  const float* aemb  = (const float*)d_in[9];
  const float* aanc  = (const float*)d_in[10];
  const float* zW    = (const float*)d_in[11];
  const float* zb    = (const float*)d_in[12];
  const float* latW  = (const float*)d_in[13];
  const float* latb  = (const float*)d_in[14];
  const float* codeW = (const float*)d_in[15];
  const float* codeb = (const float*)d_in[16];
  const float* Wq    = (const float*)d_in[17];
  const float* Wk    = (const float*)d_in[18];
  const float* Wv    = (const float*)d_in[19];
  const float* Wo    = (const float*)d_in[20];
  const float* fW    = (const float*)d_in[21];
  const float* fb    = (const float*)d_in[22];
  float* ws  = (float*)d_ws;
  float* out = (float*)d_out;

  k1_fold<<<501, 256, 0, stream>>>(chemb, aemb, zW, zb, latW, latb, codeW, codeb,
                                   Wq, Wk, Wv, Wo, fW, ws);
  k2_main<<<NMAIN + 1, 256, 0, stream>>>(z, rw, az, arw, acz, ctrl, ecov,
                                         chanc, aanc, fb, ws);
  k3_out<<<(B_N + 255) / 256, 256, 0, stream>>>(ws, out);
}